// Round 10
// baseline (255.520 us; speedup 1.0000x reference)
//
#include <hip/hip_runtime.h>
#include <hip/hip_bf16.h>

// out[b,i,j,k] = sum_{p,q,r} x[b,p,q,r] W1[p,i] W2[q,j] W3[r,k]
// Stage A contracts r, B contracts q, C contracts p (R9-validated maps,
// absmax 0.0361). R10 = software-pipelined persistent version:
//
//  - 512 persistent blocks x 4 rows grid-stride, 2 blocks/CU (70KB LDS).
//  - vmcnt queue discipline (the R7 lesson): per iter the ONLY vmem ops are
//    [chunk0 x-loads][chunk1 x-loads][out stores], in that order. Waiting on
//    a load never drains younger stores; stores drain under the NEXT iter's
//    compute. Weights come from LDS (lgkm queue) so no weight load ever
//    forces a store drain (R7's per-iter global weight reads did exactly
//    that -> 149us).
//  - split prefetch fits the 64-VGPR cap that killed R5/R6: chunk0 (16 regs,
//    fa[0..1]) issued after stage A, converted after stage B; chunk1 issued
//    there, converted after stage C. Audited peak ~60 VGPR.
//  - raw lgkm-only barriers (R5-R7 proven race-free), 4 per iter:
//    B1 yA RAW, B2 yA WAR, B3 yB RAW, B4 yB WAR (fc reads vs next stage A).
//  - nontemporal output stores (R9): out never re-read, keep L3 for x.
//
// MFMA 16x16x32 bf16 layouts (m89-verified, R3..R9-validated):
//   A/B lane l: k = 8*((l>>4)&3)+j ; C/D: col=l&15 (n), row=4*((l>>4)&3)+reg.
// Bank conflicts (~15.7M) left as-is: R9 A/B (8.4M vs 15.7M, same time)
// proved they are off the critical path.

typedef __attribute__((ext_vector_type(8))) short bf16x8;
typedef __attribute__((ext_vector_type(4))) float f32x4;

#define NROW 32768
#define NBLK 512

// LDS-only release/acquire: NO vmcnt drain -> loads/stores stay in flight.
#define BAR() do {                                          \
    asm volatile("s_waitcnt lgkmcnt(0)" ::: "memory");      \
    __builtin_amdgcn_s_barrier();                           \
    __builtin_amdgcn_sched_barrier(0);                      \
} while (0)

__device__ __forceinline__ unsigned pk2(float a, float b) {
    union { __hip_bfloat162 h; unsigned u; } v;
    v.h = __float22bfloat162_rn(make_float2(a, b));        // v_cvt_pk_bf16_f32
    return v.u;
}
__device__ __forceinline__ unsigned short b16(float a) {
    union { __hip_bfloat16 h; unsigned short u; } v;
    v.h = __float2bfloat16(a);
    return v.u;
}
__device__ __forceinline__ bf16x8 packfrag(float4 f0, float4 f1) {
    union { unsigned u[4]; bf16x8 b; } r;
    r.u[0] = pk2(f0.x, f0.y); r.u[1] = pk2(f0.z, f0.w);
    r.u[2] = pk2(f1.x, f1.y); r.u[3] = pk2(f1.z, f1.w);
    return r.b;
}

// swizzled element index: 8-elem column block XOR'd by row hash (b128-safe)
__device__ __forceinline__ int swz(int row, int col) {
    int s = ((row ^ (row >> 2) ^ (row >> 4)) & 3) << 3;
    return row * 32 + (col ^ s);
}

// LDS fragment: row-major 32-col row, 8 contiguous cols at swizzled block
__device__ __forceinline__ bf16x8 ldsfrag(const unsigned short* buf, int row, int g) {
    int s = (row ^ (row >> 2) ^ (row >> 4)) & 3;
    union { uint4 u; bf16x8 b; } cv;
    cv.u = *(const uint4*)(buf + row * 32 + 8 * (g ^ s));
    return cv.b;
}

__global__ __launch_bounds__(1024, 8) void kron3_pipe(
    const float* __restrict__ x,  const float* __restrict__ W1,
    const float* __restrict__ W2, const float* __restrict__ W3,
    float* __restrict__ out, int iters)
{
    __shared__ unsigned short buf[NROW];       // 64 KiB row workspace
    __shared__ unsigned short wlds[3 * 1024];  // 6 KiB W1^T,W2^T,W3^T (bf16)
    const int t = threadIdx.x;
    const int w = t >> 6, c = t & 15, g = (t >> 4) & 3;
    const f32x4 vzero = {0.f, 0.f, 0.f, 0.f};

    // ---- stage weights once: wlds[m][n][k] = Wm[k][n] (R7-validated map) ----
    {
        const int n = t >> 5, k = t & 31;
        wlds[0 * 1024 + swz(n, k)] = b16(W1[k * 32 + n]);
        wlds[1 * 1024 + swz(n, k)] = b16(W2[k * 32 + n]);
        wlds[2 * 1024 + swz(n, k)] = b16(W3[k * 32 + n]);
    }

    // ---- prologue: load + convert row blockIdx.x ----
    float4 fr[8];
    bf16x8 fa[4];
    {
        const float* xr = x + (size_t)blockIdx.x * NROW;
#pragma unroll
        for (int mt = 0; mt < 4; ++mt) {
            const float* s = xr + (64 * w + 16 * mt + c) * 32 + 8 * g;
            fr[2 * mt]     = ((const float4*)s)[0];
            fr[2 * mt + 1] = ((const float4*)s)[1];
        }
#pragma unroll
        for (int mt = 0; mt < 4; ++mt) fa[mt] = packfrag(fr[2 * mt], fr[2 * mt + 1]);
    }
    BAR();   // wlds visible to all waves

#pragma unroll 1
    for (int it = 0; it < iters; ++it) {
        // opaque lane id: LDS weight-frag reads loop-variant -> no LICM pinning
        int tv = t;
        asm volatile("" : "+v"(tv));
        const int cv = tv & 15, gv = (tv >> 4) & 3;
        const size_t row = (size_t)blockIdx.x + (size_t)NBLK * it;
        const bool pre = (it + 1 < iters);
        const float* xnext = x + (row + NBLK) * NROW;

        // ---- stage A: contract r.  yA[(k',p)][q] = sum_r x[(p,q),r] W3[r,k'] ----
        {
            bf16x8 wA0 = ldsfrag(wlds + 2048, cv, gv);
            bf16x8 wA1 = ldsfrag(wlds + 2048, 16 + cv, gv);
#pragma unroll
            for (int nt = 0; nt < 2; ++nt) {
                const int kp = 16 * nt + c;
                const bf16x8 wA = nt ? wA1 : wA0;
#pragma unroll
                for (int mt = 0; mt < 4; ++mt) {
                    f32x4 a = __builtin_amdgcn_mfma_f32_16x16x32_bf16(fa[mt], wA, vzero, 0, 0, 0);
                    const int p  = 2 * w + (mt >> 1);
                    const int q0 = 16 * (mt & 1) + 4 * g;
                    *(uint2*)(buf + swz(kp * 32 + p, q0)) =
                        make_uint2(pk2(a[0], a[1]), pk2(a[2], a[3]));
                }
            }
        }
        // issue chunk0 of next row (oldest vmem ops this iter)
        if (pre) {
#pragma unroll
            for (int mt = 0; mt < 2; ++mt) {
                const float* s = xnext + (64 * w + 16 * mt + c) * 32 + 8 * g;
                fr[2 * mt]     = ((const float4*)s)[0];
                fr[2 * mt + 1] = ((const float4*)s)[1];
            }
        }
        BAR();   // B1: yA complete (RAW; stage-A writes are cross-wave)

        // ---- stage B fragments: A-operand rows m'=(k',p), k-dim = q ----
        bf16x8 fb[4];
#pragma unroll
        for (int mt = 0; mt < 4; ++mt)
            fb[mt] = ldsfrag(buf, 64 * w + 16 * mt + c, g);
        BAR();   // B2: all yA reads retired before yB overwrites (WAR)

        // ---- stage B: contract q.  yB[(j,k')][p] = sum_q yA[(k',p)][q] W2[q,j] ----
        {
            bf16x8 wB0 = ldsfrag(wlds + 1024, cv, gv);
            bf16x8 wB1 = ldsfrag(wlds + 1024, 16 + cv, gv);
#pragma unroll
            for (int nt = 0; nt < 2; ++nt) {
                const int j = 16 * nt + c;
                const bf16x8 wB = nt ? wB1 : wB0;
#pragma unroll
                for (int mt = 0; mt < 4; ++mt) {
                    f32x4 a = __builtin_amdgcn_mfma_f32_16x16x32_bf16(fb[mt], wB, vzero, 0, 0, 0);
                    const int kq = 2 * w + (mt >> 1);
                    const int p0 = 16 * (mt & 1) + 4 * g;
                    *(uint2*)(buf + swz(j * 32 + kq, p0)) =
                        make_uint2(pk2(a[0], a[1]), pk2(a[2], a[3]));
                }
            }
        }
        // convert chunk0 (wait leaves chunk1/stores free), issue chunk1
        if (pre) {
            fa[0] = packfrag(fr[0], fr[1]);
            fa[1] = packfrag(fr[2], fr[3]);
#pragma unroll
            for (int mt = 2; mt < 4; ++mt) {
                const float* s = xnext + (64 * w + 16 * mt + c) * 32 + 8 * g;
                fr[2 * mt]     = ((const float4*)s)[0];
                fr[2 * mt + 1] = ((const float4*)s)[1];
            }
        }
        BAR();   // B3: yB complete (RAW)

        // ---- stage C: contract p.  out[i,j,k] = sum_p yB[(j,k)][p] W1[p,i] ----
        bf16x8 fc[4];
#pragma unroll
        for (int mt = 0; mt < 4; ++mt)
            fc[mt] = ldsfrag(buf, 64 * w + 16 * mt + c, g);
        BAR();   // B4: fc reads retired; next iter's stage-A writes safe (WAR)

        {
            bf16x8 wC0 = ldsfrag(wlds, cv, gv);
            bf16x8 wC1 = ldsfrag(wlds, 16 + cv, gv);
            float* orow = out + row * NROW;
#pragma unroll
            for (int nt = 0; nt < 2; ++nt) {
                const int i = 16 * nt + c;
                const bf16x8 wC = nt ? wC1 : wC0;
#pragma unroll
                for (int mt = 0; mt < 4; ++mt) {
                    f32x4 a = __builtin_amdgcn_mfma_f32_16x16x32_bf16(fc[mt], wC, vzero, 0, 0, 0);
                    const int j  = 2 * w + (mt >> 1);
                    const int k0 = 16 * (mt & 1) + 4 * g;
                    __builtin_nontemporal_store(a,
                        (f32x4*)(orow + i * 1024 + j * 32 + k0));   // drain under next iter
                }
            }
        }
        // convert chunk1 (wait leaves this iter's stores in flight)
        if (pre) {
            fa[2] = packfrag(fr[4], fr[5]);
            fa[3] = packfrag(fr[6], fr[7]);
        }
    }
}

extern "C" void kernel_launch(void* const* d_in, const int* in_sizes, int n_in,
                              void* d_out, int out_size, void* d_ws, size_t ws_size,
                              hipStream_t stream) {
    const float* x  = (const float*)d_in[0];
    const float* W1 = (const float*)d_in[1];
    const float* W2 = (const float*)d_in[2];
    const float* W3 = (const float*)d_in[3];
    float* outp = (float*)d_out;

    const int batch = in_sizes[0] / NROW;             // 2048
    const int iters = batch / NBLK;                   // 4
    kron3_pipe<<<dim3(NBLK), dim3(1024), 0, stream>>>(x, W1, W2, W3, outp, iters);
}

// Round 11
// 156.715 us; speedup vs baseline: 1.6305x; 1.6305x over previous
//
#include <hip/hip_runtime.h>
#include <hip/hip_bf16.h>

// out[b,i,j,k] = sum_{p,q,r} x[b,p,q,r] W1[p,i] W2[q,j] W3[r,k]
// Stage A contracts r, B contracts q, C contracts p (R9-validated maps).
//
// R11: k'-HALF SPLIT. Stages A/B are independent per k'; only stage A's
// x-read is shared between halves. One block = one (row, k'-half):
//   - 512 threads (8 waves), 32 KB LDS -> 4 blocks/CU (vs 2), 4096 blocks.
//     R10 post-mortem: 2 big blocks/CU phase-lock -> HBM starved ~50%.
//     4 small independent actors keep requests outstanding continuously.
//   - stage A streams: with one n-tile, each x fragment is used ONCE ->
//     load, pack, mfma, ds_write; no fa[] array. Register peak ~40 fits the
//     64-VGPR cap that __launch_bounds__(512,4) empirically enforces (R5).
//   - plain stores (R9's nontemporal: +124MB WRITE, 0 time), plain
//     __syncthreads (pipelined persistent variants refuted R5-R10).
//   - cost: both halves read the full x row; adjacent blockIdx -> 2nd read
//     L2/L3-absorbed (FETCH gate: expect 140-270MB).
//
// LDS 512x32 bf16 (32KB), in-place across stages, same swz as R3-R9:
//   yA : buf[(kl*32+p)][q]   kl = k'-16h in [0,16)
//   yB : buf[(j*16+kl)][p]
// MFMA 16x16x32 bf16 layouts (m89-verified, R3..R10-validated):
//   A/B lane l: row/col = l&15, k = 8*((l>>4)&3)+j
//   C/D: col = l&15 (n), row-in-tile = 4*((l>>4)&3)+reg (m).
// Bank conflicts left as-is (R8/R9 A/B: 8.4M vs 15.7M, same time -> off path).

typedef __attribute__((ext_vector_type(8))) short bf16x8;
typedef __attribute__((ext_vector_type(4))) float f32x4;

#define NROW 32768

__device__ __forceinline__ unsigned pk2(float a, float b) {
    union { __hip_bfloat162 h; unsigned u; } v;
    v.h = __float22bfloat162_rn(make_float2(a, b));        // v_cvt_pk_bf16_f32
    return v.u;
}
__device__ __forceinline__ bf16x8 packfrag(float4 f0, float4 f1) {
    union { unsigned u[4]; bf16x8 b; } r;
    r.u[0] = pk2(f0.x, f0.y); r.u[1] = pk2(f0.z, f0.w);
    r.u[2] = pk2(f1.x, f1.y); r.u[3] = pk2(f1.z, f1.w);
    return r.b;
}

// swizzled element index: 8-elem column block XOR'd by row hash (b128-safe;
// 4-aligned sub-blocks survive: s only flips bits 3..4 of the column)
__device__ __forceinline__ int swz(int row, int col) {
    int s = ((row ^ (row >> 2) ^ (row >> 4)) & 3) << 3;
    return row * 32 + (col ^ s);
}

// weight fragment: lane (c,g) holds W[k=8g+j][n=16h+c], j=0..7 (k-consecutive)
__device__ __forceinline__ bf16x8 wfrag(const float* __restrict__ W, int h, int c, int g) {
    union { unsigned u[4]; bf16x8 b; } r;
#pragma unroll
    for (int jj = 0; jj < 4; ++jj) {
        float a = W[(8 * g + 2 * jj    ) * 32 + 16 * h + c];
        float b = W[(8 * g + 2 * jj + 1) * 32 + 16 * h + c];
        r.u[jj] = pk2(a, b);
    }
    return r.b;
}

// LDS fragment: row-major 32-col row, 8 contiguous cols at swizzled block
__device__ __forceinline__ bf16x8 ldsfrag(const unsigned short* buf, int row, int g) {
    int s = (row ^ (row >> 2) ^ (row >> 4)) & 3;
    union { uint4 u; bf16x8 b; } cv;
    cv.u = *(const uint4*)(buf + row * 32 + 8 * (g ^ s));
    return cv.b;
}

__global__ __launch_bounds__(512, 4) void kron3_half(
    const float* __restrict__ x,  const float* __restrict__ W1,
    const float* __restrict__ W2, const float* __restrict__ W3,
    float* __restrict__ out)
{
    __shared__ unsigned short buf[16384];           // 32 KiB bf16 (512 x 32)
    const int t = threadIdx.x;
    const int w = t >> 6, c = t & 15, g = (t >> 4) & 3;
    const int h = blockIdx.x & 1;                   // k' half
    const float* __restrict__ xrow = x   + (size_t)(blockIdx.x >> 1) * NROW;
    float* __restrict__       orow = out + (size_t)(blockIdx.x >> 1) * NROW;
    const f32x4 vzero = {0.f, 0.f, 0.f, 0.f};

    // ---- stage A: contract r.  yA[(kl,p)][q] = sum_r x[(p,q),r] W3[r,16h+kl]
    // streaming: fragment m-row = 128w+16mt+c (p=4w+(mt>>1), q=16(mt&1)+c);
    // D lane (c,g) reg rg: kl=c, p=4w+(mt>>1), q=16(mt&1)+4g+rg -> packed b64
    {
        const bf16x8 wA = wfrag(W3, h, c, g);
#pragma unroll
        for (int mt = 0; mt < 8; ++mt) {
            const float* s = xrow + (128 * w + 16 * mt + c) * 32 + 8 * g;
            float4 f0 = ((const float4*)s)[0];
            float4 f1 = ((const float4*)s)[1];
            f32x4 a = __builtin_amdgcn_mfma_f32_16x16x32_bf16(
                packfrag(f0, f1), wA, vzero, 0, 0, 0);
            const int p  = 4 * w + (mt >> 1);
            const int q0 = 16 * (mt & 1) + 4 * g;
            *(uint2*)(buf + swz(c * 32 + p, q0)) =
                make_uint2(pk2(a[0], a[1]), pk2(a[2], a[3]));
        }
    }
    __syncthreads();   // S1: yA complete (cross-wave RAW)

    // ---- stage B fragments: rows m'=(kl,p): kl=2w+(mt>>1), p=16(mt&1)+c ----
    bf16x8 fb[4];
#pragma unroll
    for (int mt = 0; mt < 4; ++mt)
        fb[mt] = ldsfrag(buf, 64 * w + 16 * mt + c, g);
    __syncthreads();   // S2: all yA reads retired before yB overwrites (WAR)

    // ---- stage B: contract q.  yB[(j,kl)][p] = sum_q yA[(kl,p)][q] W2[q,j]
    // D lane (c,g) reg rg: kl=2w+(mt>>1), p=16(mt&1)+4g+rg (consecutive), j=16jt+c
    {
        bf16x8 wB[2] = { wfrag(W2, 0, c, g), wfrag(W2, 1, c, g) };
#pragma unroll
        for (int jt = 0; jt < 2; ++jt) {
#pragma unroll
            for (int mt = 0; mt < 4; ++mt) {
                f32x4 a = __builtin_amdgcn_mfma_f32_16x16x32_bf16(fb[mt], wB[jt], vzero, 0, 0, 0);
                const int row = (16 * jt + c) * 16 + 2 * w + (mt >> 1);
                const int p0  = 16 * (mt & 1) + 4 * g;
                *(uint2*)(buf + swz(row, p0)) =
                    make_uint2(pk2(a[0], a[1]), pk2(a[2], a[3]));
            }
        }
    }
    __syncthreads();   // S3: yB complete (RAW)

    // ---- stage C: contract p.  out[i,j,16h+kl] = sum_p yB[(j,kl)][p] W1[p,i]
    // fragment rows m''=(j,kl): j=4w+mt, kl=c; D: j=4w+mt, kl=4g+rg, i=16nt+c
    bf16x8 fc[4];
#pragma unroll
    for (int mt = 0; mt < 4; ++mt)
        fc[mt] = ldsfrag(buf, 64 * w + 16 * mt + c, g);

    {
        bf16x8 wC[2] = { wfrag(W1, 0, c, g), wfrag(W1, 1, c, g) };
#pragma unroll
        for (int nt = 0; nt < 2; ++nt) {
            const int i = 16 * nt + c;
#pragma unroll
            for (int mt = 0; mt < 4; ++mt) {
                f32x4 a = __builtin_amdgcn_mfma_f32_16x16x32_bf16(fc[mt], wC[nt], vzero, 0, 0, 0);
                const int j  = 4 * w + mt;
                const int k0 = 16 * h + 4 * g;
                *(float4*)(orow + i * 1024 + j * 32 + k0) =
                    make_float4(a[0], a[1], a[2], a[3]);
            }
        }
    }
}

extern "C" void kernel_launch(void* const* d_in, const int* in_sizes, int n_in,
                              void* d_out, int out_size, void* d_ws, size_t ws_size,
                              hipStream_t stream) {
    const float* x  = (const float*)d_in[0];
    const float* W1 = (const float*)d_in[1];
    const float* W2 = (const float*)d_in[2];
    const float* W3 = (const float*)d_in[3];
    float* outp = (float*)d_out;

    const int batch = in_sizes[0] / NROW;             // 2048
    kron3_half<<<dim3(batch * 2), dim3(512), 0, stream>>>(x, W1, W2, W3, outp);
}